// Round 4
// baseline (1522.501 us; speedup 1.0000x reference)
//
#include <hip/hip_runtime.h>

#define CH 128
#define MAXB 1024       // max buckets (128 rows each)
#define BIN_CHUNK 16384 // edges per k_bin block

// ============================ fallback path (R1) ============================
__global__ void k_init(float4* __restrict__ out, int n4) {
  int i = blockIdx.x * blockDim.x + threadIdx.x;
  int stride = gridDim.x * blockDim.x;
  float4 z = make_float4(0.f, 0.f, 0.f, 0.f);
  for (; i < n4; i += stride) out[i] = z;
}

__global__ void k_scatter(const float* __restrict__ x,
                          const int* __restrict__ rows,
                          const int* __restrict__ cols,
                          const float* __restrict__ vals,
                          float* __restrict__ out, int nEdges) {
  long long total = (long long)nEdges * CH;
  long long stride = (long long)gridDim.x * blockDim.x;
  for (long long i = (long long)blockIdx.x * blockDim.x + threadIdx.x;
       i < total; i += stride) {
    int e = (int)(i >> 7);
    int c = (int)(i & 127);
    unsafeAtomicAdd(out + (((long long)rows[e]) << 7) + c,
                    vals[e] * x[(((long long)cols[e]) << 7) + c]);
  }
}

// ===================== bucket histogram (782 buckets) =======================
__global__ __launch_bounds__(256) void k_histB(const int* __restrict__ rows,
                                               int* __restrict__ bcnt, int nE,
                                               int nB) {
  __shared__ int lh[MAXB];
  int tid = threadIdx.x;
  for (int i = tid; i < nB; i += 256) lh[i] = 0;
  __syncthreads();
  int stride = gridDim.x * blockDim.x;
  for (int i = blockIdx.x * blockDim.x + tid; i < nE; i += stride)
    atomicAdd(&lh[rows[i] >> 7], 1);
  __syncthreads();
  for (int t = tid; t < nB; t += 256)
    if (lh[t]) atomicAdd(&bcnt[t], lh[t]);
}

// ================= exclusive scan over <=1024 buckets (1 block) =============
__global__ __launch_bounds__(256) void k_scanB(const int* __restrict__ bcnt,
                                               int* __restrict__ bptr,
                                               int* __restrict__ cursor,
                                               int nB) {
  __shared__ int s[256];
  int t = threadIdx.x;
  int v[4];
  int sum = 0;
#pragma unroll
  for (int k = 0; k < 4; ++k) {
    int idx = t * 4 + k;
    v[k] = (idx < nB) ? bcnt[idx] : 0;
    sum += v[k];
  }
  s[t] = sum;
  __syncthreads();
  for (int off = 1; off < 256; off <<= 1) {
    int add = (t >= off) ? s[t - off] : 0;
    __syncthreads();
    s[t] += add;
    __syncthreads();
  }
  int run = s[t] - sum;
#pragma unroll
  for (int k = 0; k < 4; ++k) {
    int idx = t * 4 + k;
    if (idx < nB) {
      bptr[idx] = run;
      cursor[idx] = run;
    }
    run += v[k];
  }
  if (t == 255) bptr[nB] = run;
}

// ========== binning: chunk-local LDS histogram -> one reserve per bucket ====
// key = (row&127)<<25 | col ; payload val. Writes per bucket per block are
// contiguous (~BIN_CHUNK/nB entries) -> dense lines instead of 8B scatter.
__global__ __launch_bounds__(256) void k_bin(const int* __restrict__ rows,
                                             const int* __restrict__ cols,
                                             const float* __restrict__ vals,
                                             int* __restrict__ cursor,
                                             int2* __restrict__ ecv, int nE,
                                             int nB) {
  __shared__ int lhist[MAXB];
  __shared__ int lbase[MAXB];
  int tid = threadIdx.x;
  int b0 = blockIdx.x * BIN_CHUNK;
  int b1 = min(nE, b0 + BIN_CHUNK);
  for (int i = tid; i < nB; i += 256) lhist[i] = 0;
  __syncthreads();
  for (int i = b0 + tid; i < b1; i += 256) atomicAdd(&lhist[rows[i] >> 7], 1);
  __syncthreads();
  for (int t = tid; t < nB; t += 256) {
    int c = lhist[t];
    lbase[t] = c ? atomicAdd(&cursor[t], c) : 0;
  }
  __syncthreads();
  for (int i = b0 + tid; i < b1; i += 256) {
    int r = rows[i];
    int bk = r >> 7;
    int p = atomicAdd(&lbase[bk], 1);
    unsigned key = ((unsigned)(r & 127) << 25) | (unsigned)cols[i];
    ecv[p] = make_int2((int)key, __float_as_int(vals[i]));
  }
}

// ========== aggregate: one block per 128-row bucket, LDS f32 accumulator ====
// Wave loads 64 edges coalesced; shfl-broadcast each; 64 lanes float2-load
// x[col] and ds_add into acc[lrow][2*lane] (2-way bank alias: free).
__global__ __launch_bounds__(512) void k_agg(const float* __restrict__ x,
                                             const int* __restrict__ bptr,
                                             const int2* __restrict__ ecv,
                                             float* __restrict__ out,
                                             int nNodes) {
  __shared__ float acc[CH * CH];  // 64KB
  int tid = threadIdx.x;
  float4* accv = (float4*)acc;
  for (int i = tid; i < CH * 32; i += 512)
    accv[i] = make_float4(0.f, 0.f, 0.f, 0.f);
  __syncthreads();
  int b = blockIdx.x;
  int e0 = bptr[b], e1 = bptr[b + 1];
  int wave = tid >> 6, lane = tid & 63;
  int c0 = lane << 1;
  for (int base = e0 + wave * 64; base < e1; base += 512) {
    int m = e1 - base;
    if (m > 64) m = 64;
    unsigned key = 0;
    float v = 0.f;
    if (lane < m) {
      int2 e = ecv[base + lane];
      key = (unsigned)e.x;
      v = __int_as_float(e.y);
    }
    if (m == 64) {
#pragma unroll 8
      for (int j = 0; j < 64; ++j) {
        unsigned kj = (unsigned)__shfl((int)key, j);
        float vj = __shfl(v, j);
        int col = (int)(kj & 0x1FFFFFFu);
        int lrow = (int)(kj >> 25);
        const float2 xv =
            *reinterpret_cast<const float2*>(x + (((long long)col) << 7) + c0);
        atomicAdd(&acc[(lrow << 7) + c0], vj * xv.x);
        atomicAdd(&acc[(lrow << 7) + c0 + 1], vj * xv.y);
      }
    } else {
      for (int j = 0; j < m; ++j) {
        unsigned kj = (unsigned)__shfl((int)key, j);
        float vj = __shfl(v, j);
        int col = (int)(kj & 0x1FFFFFFu);
        int lrow = (int)(kj >> 25);
        const float2 xv =
            *reinterpret_cast<const float2*>(x + (((long long)col) << 7) + c0);
        atomicAdd(&acc[(lrow << 7) + c0], vj * xv.x);
        atomicAdd(&acc[(lrow << 7) + c0 + 1], vj * xv.y);
      }
    }
  }
  __syncthreads();
  int row0 = b << 7;
  for (int i = tid; i < CH * 32; i += 512) {
    int r = row0 + (i >> 5);
    if (r < nNodes)
      reinterpret_cast<float4*>(out)[(((long long)r) << 5) + (i & 31)] =
          accv[i];
  }
}

// ==================== projection: out = agg @ W^T + b (in place) ============
#define PRJ_ROWS 64
__global__ __launch_bounds__(256) void k_project(float* __restrict__ out,
                                                 const float* __restrict__ W,
                                                 const float* __restrict__ bias,
                                                 int nNodes) {
  __shared__ float sWt[CH * CH];  // [c][o], xor-swizzled
  __shared__ float sA[8 * 68];    // [kc][r], padded
  int tid = threadIdx.x;
  int og = tid & 31, rg = tid >> 5;
  for (int idx = tid; idx < CH * CH; idx += 256) {
    int o = idx >> 7, c = idx & 127;
    sWt[(c * CH + o) ^ ((c & 31) << 2)] = W[idx];
  }
  int row0 = blockIdx.x * PRJ_ROWS;
  float acc[8][4];
#pragma unroll
  for (int i = 0; i < 8; ++i)
#pragma unroll
    for (int j = 0; j < 4; ++j) acc[i][j] = 0.f;
  int sr = tid >> 2;
  int skc = (tid & 3) << 1;
  __syncthreads();
  for (int kk = 0; kk < CH; kk += 8) {
    float2 av = make_float2(0.f, 0.f);
    int grow = row0 + sr;
    if (grow < nNodes)
      av = *reinterpret_cast<const float2*>(out + (((long long)grow) << 7) +
                                            kk + skc);
    sA[skc * 68 + sr] = av.x;
    sA[(skc + 1) * 68 + sr] = av.y;
    __syncthreads();
#pragma unroll
    for (int kc = 0; kc < 8; ++kc) {
      int c = kk + kc;
      const float4 w4 = *reinterpret_cast<const float4*>(
          &sWt[(c * CH + (og << 2)) ^ ((c & 31) << 2)]);
      const float4 a0 =
          *reinterpret_cast<const float4*>(&sA[kc * 68 + (rg << 3)]);
      const float4 a1 =
          *reinterpret_cast<const float4*>(&sA[kc * 68 + (rg << 3) + 4]);
      acc[0][0] = fmaf(a0.x, w4.x, acc[0][0]);
      acc[0][1] = fmaf(a0.x, w4.y, acc[0][1]);
      acc[0][2] = fmaf(a0.x, w4.z, acc[0][2]);
      acc[0][3] = fmaf(a0.x, w4.w, acc[0][3]);
      acc[1][0] = fmaf(a0.y, w4.x, acc[1][0]);
      acc[1][1] = fmaf(a0.y, w4.y, acc[1][1]);
      acc[1][2] = fmaf(a0.y, w4.z, acc[1][2]);
      acc[1][3] = fmaf(a0.y, w4.w, acc[1][3]);
      acc[2][0] = fmaf(a0.z, w4.x, acc[2][0]);
      acc[2][1] = fmaf(a0.z, w4.y, acc[2][1]);
      acc[2][2] = fmaf(a0.z, w4.z, acc[2][2]);
      acc[2][3] = fmaf(a0.z, w4.w, acc[2][3]);
      acc[3][0] = fmaf(a0.w, w4.x, acc[3][0]);
      acc[3][1] = fmaf(a0.w, w4.y, acc[3][1]);
      acc[3][2] = fmaf(a0.w, w4.z, acc[3][2]);
      acc[3][3] = fmaf(a0.w, w4.w, acc[3][3]);
      acc[4][0] = fmaf(a1.x, w4.x, acc[4][0]);
      acc[4][1] = fmaf(a1.x, w4.y, acc[4][1]);
      acc[4][2] = fmaf(a1.x, w4.z, acc[4][2]);
      acc[4][3] = fmaf(a1.x, w4.w, acc[4][3]);
      acc[5][0] = fmaf(a1.y, w4.x, acc[5][0]);
      acc[5][1] = fmaf(a1.y, w4.y, acc[5][1]);
      acc[5][2] = fmaf(a1.y, w4.z, acc[5][2]);
      acc[5][3] = fmaf(a1.y, w4.w, acc[5][3]);
      acc[6][0] = fmaf(a1.z, w4.x, acc[6][0]);
      acc[6][1] = fmaf(a1.z, w4.y, acc[6][1]);
      acc[6][2] = fmaf(a1.z, w4.z, acc[6][2]);
      acc[6][3] = fmaf(a1.z, w4.w, acc[6][3]);
      acc[7][0] = fmaf(a1.w, w4.x, acc[7][0]);
      acc[7][1] = fmaf(a1.w, w4.y, acc[7][1]);
      acc[7][2] = fmaf(a1.w, w4.z, acc[7][2]);
      acc[7][3] = fmaf(a1.w, w4.w, acc[7][3]);
    }
    __syncthreads();
  }
  int o0 = og << 2;
  const float4 bv = *reinterpret_cast<const float4*>(&bias[o0]);
#pragma unroll
  for (int i = 0; i < 8; ++i) {
    int r = row0 + (rg << 3) + i;
    if (r < nNodes) {
      float4 res = make_float4(acc[i][0] + bv.x, acc[i][1] + bv.y,
                               acc[i][2] + bv.z, acc[i][3] + bv.w);
      *reinterpret_cast<float4*>(out + (((long long)r) << 7) + o0) = res;
    }
  }
}

extern "C" void kernel_launch(void* const* d_in, const int* in_sizes, int n_in,
                              void* d_out, int out_size, void* d_ws,
                              size_t ws_size, hipStream_t stream) {
  const float* x = (const float*)d_in[0];
  const int* rows = (const int*)d_in[1];
  const int* cols = (const int*)d_in[2];
  const float* vals = (const float*)d_in[3];
  const float* W = (const float*)d_in[4];
  const float* b = (const float*)d_in[5];
  float* out = (float*)d_out;

  int nEdges = in_sizes[1];
  int nNodes = in_sizes[0] / CH;
  int nPrjBlocks = (nNodes + PRJ_ROWS - 1) / PRJ_ROWS;
  int nB = (nNodes + 127) >> 7;

  // ws layout (ints): bptr[nB+1] | cursor[nB] | bcnt[nB] | pad | ecv[2E]
  size_t head = (size_t)(3 * nB + 1);
  size_t ecvOff = (head + 1) & ~(size_t)1;  // 8B align
  size_t needBytes = (ecvOff + 2 * (size_t)nEdges) * 4;

  if (ws_size < needBytes || nB > MAXB || nNodes >= (1 << 25)) {
    hipLaunchKernelGGL(k_init, dim3(2048), dim3(256), 0, stream, (float4*)out,
                       out_size / 4);
    hipLaunchKernelGGL(k_scatter, dim3(4096), dim3(256), 0, stream, x, rows,
                       cols, vals, out, nEdges);
    hipLaunchKernelGGL(k_project, dim3(nPrjBlocks), dim3(256), 0, stream, out,
                       W, b, nNodes);
    return;
  }

  int* wsI = (int*)d_ws;
  int* bptr = wsI;
  int* cursor = bptr + (nB + 1);
  int* bcnt = cursor + nB;
  int2* ecv = (int2*)(wsI + ecvOff);

  int nBinBlocks = (nEdges + BIN_CHUNK - 1) / BIN_CHUNK;

  hipMemsetAsync(bcnt, 0, (size_t)nB * 4, stream);
  hipLaunchKernelGGL(k_histB, dim3(512), dim3(256), 0, stream, rows, bcnt,
                     nEdges, nB);
  hipLaunchKernelGGL(k_scanB, dim3(1), dim3(256), 0, stream, bcnt, bptr,
                     cursor, nB);
  hipLaunchKernelGGL(k_bin, dim3(nBinBlocks), dim3(256), 0, stream, rows, cols,
                     vals, cursor, ecv, nEdges, nB);
  hipLaunchKernelGGL(k_agg, dim3(nB), dim3(512), 0, stream, x, bptr, ecv, out,
                     nNodes);
  hipLaunchKernelGGL(k_project, dim3(nPrjBlocks), dim3(256), 0, stream, out, W,
                     b, nNodes);
}

// Round 5
// 344.126 us; speedup vs baseline: 4.4243x; 4.4243x over previous
//
#include <hip/hip_runtime.h>

#define CH 128
#define MAXB 1024        // max buckets (128 rows each)
#define BIN_CHUNK 8192   // edges per k_bin block
#define AGG_CAP 4096     // edges per LDS chunk in k_agg
#define AGG_THREADS 512

// ============================ fallback path (R1) ============================
__global__ void k_init(float4* __restrict__ out, int n4) {
  int i = blockIdx.x * blockDim.x + threadIdx.x;
  int stride = gridDim.x * blockDim.x;
  float4 z = make_float4(0.f, 0.f, 0.f, 0.f);
  for (; i < n4; i += stride) out[i] = z;
}

__global__ void k_scatter(const float* __restrict__ x,
                          const int* __restrict__ rows,
                          const int* __restrict__ cols,
                          const float* __restrict__ vals,
                          float* __restrict__ out, int nEdges) {
  long long total = (long long)nEdges * CH;
  long long stride = (long long)gridDim.x * blockDim.x;
  for (long long i = (long long)blockIdx.x * blockDim.x + threadIdx.x;
       i < total; i += stride) {
    int e = (int)(i >> 7);
    int c = (int)(i & 127);
    unsafeAtomicAdd(out + (((long long)rows[e]) << 7) + c,
                    vals[e] * x[(((long long)cols[e]) << 7) + c]);
  }
}

// ===================== bucket histogram =====================================
__global__ __launch_bounds__(256) void k_histB(const int* __restrict__ rows,
                                               int* __restrict__ bcnt, int nE,
                                               int nB) {
  __shared__ int lh[MAXB];
  int tid = threadIdx.x;
  for (int i = tid; i < nB; i += 256) lh[i] = 0;
  __syncthreads();
  int stride = gridDim.x * blockDim.x;
  for (int i = blockIdx.x * blockDim.x + tid; i < nE; i += stride)
    atomicAdd(&lh[rows[i] >> 7], 1);
  __syncthreads();
  for (int t = tid; t < nB; t += 256)
    if (lh[t]) atomicAdd(&bcnt[t], lh[t]);
}

// ================= exclusive scan over <=1024 buckets (1 block) =============
__global__ __launch_bounds__(256) void k_scanB(const int* __restrict__ bcnt,
                                               int* __restrict__ bptr,
                                               int* __restrict__ cursor,
                                               int nB) {
  __shared__ int s[256];
  int t = threadIdx.x;
  int v[4];
  int sum = 0;
#pragma unroll
  for (int k = 0; k < 4; ++k) {
    int idx = t * 4 + k;
    v[k] = (idx < nB) ? bcnt[idx] : 0;
    sum += v[k];
  }
  s[t] = sum;
  __syncthreads();
  for (int off = 1; off < 256; off <<= 1) {
    int add = (t >= off) ? s[t - off] : 0;
    __syncthreads();
    s[t] += add;
    __syncthreads();
  }
  int run = s[t] - sum;
#pragma unroll
  for (int k = 0; k < 4; ++k) {
    int idx = t * 4 + k;
    if (idx < nB) {
      bptr[idx] = run;
      cursor[idx] = run;
    }
    run += v[k];
  }
  if (t == 255) bptr[nB] = run;
}

// ========== binning: chunk-local LDS histogram -> one reserve per bucket ====
// key = (row&127)<<25 | col ; payload val. Per-bucket writes are contiguous
// runs (~BIN_CHUNK/nB entries) -> dense cache lines, low write amplification.
__global__ __launch_bounds__(256) void k_bin(const int* __restrict__ rows,
                                             const int* __restrict__ cols,
                                             const float* __restrict__ vals,
                                             int* __restrict__ cursor,
                                             int2* __restrict__ ecv, int nE,
                                             int nB) {
  __shared__ int lhist[MAXB];
  __shared__ int lbase[MAXB];
  int tid = threadIdx.x;
  int b0 = blockIdx.x * BIN_CHUNK;
  int b1 = min(nE, b0 + BIN_CHUNK);
  for (int i = tid; i < nB; i += 256) lhist[i] = 0;
  __syncthreads();
  for (int i = b0 + tid; i < b1; i += 256) atomicAdd(&lhist[rows[i] >> 7], 1);
  __syncthreads();
  for (int t = tid; t < nB; t += 256) {
    int c = lhist[t];
    lbase[t] = c ? atomicAdd(&cursor[t], c) : 0;
  }
  __syncthreads();
  for (int i = b0 + tid; i < b1; i += 256) {
    int r = rows[i];
    int bk = r >> 7;
    int p = atomicAdd(&lbase[bk], 1);
    unsigned key = ((unsigned)(r & 127) << 25) | (unsigned)cols[i];
    ecv[p] = make_int2((int)key, __float_as_int(vals[i]));
  }
}

// ========== aggregate: block per bucket; LDS row-regroup; register acc ======
// Per 4096-edge chunk: int-LDS histogram of local rows -> scan -> scatter
// (col,val) row-grouped into LDS. Then wave w accumulates rows w*16..w*16+15
// in float2 registers, streaming edge meta from LDS (broadcast) and gathering
// x rows with coalesced 512B float2 loads. No float atomics anywhere.
__global__ __launch_bounds__(AGG_THREADS) void k_agg(
    const float* __restrict__ x, const int* __restrict__ bptr,
    const int2* __restrict__ ecv, float* __restrict__ out, int nNodes) {
  __shared__ unsigned skey[AGG_CAP];
  __shared__ float sval[AGG_CAP];
  __shared__ int rcnt[CH];
  __shared__ int roff[CH];
  __shared__ int rcur[CH];
  __shared__ int stmp[CH];
  int tid = threadIdx.x;
  int wave = tid >> 6, lane = tid & 63;
  int c0 = lane << 1;
  int b = blockIdx.x;
  int e0 = bptr[b], e1 = bptr[b + 1];
  float2 acc[16];
#pragma unroll
  for (int i = 0; i < 16; ++i) acc[i] = make_float2(0.f, 0.f);

  for (int base = e0; base < e1; base += AGG_CAP) {
    int cnt = min(AGG_CAP, e1 - base);
    if (tid < CH) rcnt[tid] = 0;
    __syncthreads();
    // pass A: local-row histogram (native int LDS atomics)
    for (int i = tid; i < cnt; i += AGG_THREADS)
      atomicAdd(&rcnt[((unsigned)ecv[base + i].x) >> 25], 1);
    __syncthreads();
    // exclusive scan of 128 counters
    if (tid < CH) stmp[tid] = rcnt[tid];
    __syncthreads();
    for (int off = 1; off < CH; off <<= 1) {
      int v = 0;
      if (tid < CH && tid >= off) v = stmp[tid - off];
      __syncthreads();
      if (tid < CH) stmp[tid] += v;
      __syncthreads();
    }
    if (tid < CH) {
      int o = stmp[tid] - rcnt[tid];
      roff[tid] = o;
      rcur[tid] = o;
    }
    __syncthreads();
    // pass B: scatter into row-grouped LDS arrays
    for (int i = tid; i < cnt; i += AGG_THREADS) {
      int2 e = ecv[base + i];
      unsigned key = (unsigned)e.x;
      int lr = (int)(key >> 25);
      int p = atomicAdd(&rcur[lr], 1);
      skey[p] = key & 0x1FFFFFFu;
      sval[p] = __int_as_float(e.y);
    }
    __syncthreads();
    // pass C: register accumulation, 16 rows per wave
#pragma unroll
    for (int i = 0; i < 16; ++i) {
      int lr = (wave << 4) + i;
      int j0 = roff[lr];
      int j1 = j0 + rcnt[lr];
      for (int j = j0; j < j1; ++j) {
        int col = (int)skey[j];
        float v = sval[j];
        const float2 xv =
            *reinterpret_cast<const float2*>(x + (((long long)col) << 7) + c0);
        acc[i].x = fmaf(v, xv.x, acc[i].x);
        acc[i].y = fmaf(v, xv.y, acc[i].y);
      }
    }
    __syncthreads();
  }
  int row0 = b << 7;
#pragma unroll
  for (int i = 0; i < 16; ++i) {
    int r = row0 + (wave << 4) + i;
    if (r < nNodes)
      *reinterpret_cast<float2*>(out + (((long long)r) << 7) + c0) = acc[i];
  }
}

// ==================== projection: out = agg @ W^T + b (in place) ============
#define PRJ_ROWS 64
__global__ __launch_bounds__(256) void k_project(float* __restrict__ out,
                                                 const float* __restrict__ W,
                                                 const float* __restrict__ bias,
                                                 int nNodes) {
  __shared__ float sWt[CH * CH];  // [c][o], xor-swizzled
  __shared__ float sA[8 * 68];    // [kc][r], padded
  int tid = threadIdx.x;
  int og = tid & 31, rg = tid >> 5;
  for (int idx = tid; idx < CH * CH; idx += 256) {
    int o = idx >> 7, c = idx & 127;
    sWt[(c * CH + o) ^ ((c & 31) << 2)] = W[idx];
  }
  int row0 = blockIdx.x * PRJ_ROWS;
  float acc[8][4];
#pragma unroll
  for (int i = 0; i < 8; ++i)
#pragma unroll
    for (int j = 0; j < 4; ++j) acc[i][j] = 0.f;
  int sr = tid >> 2;
  int skc = (tid & 3) << 1;
  __syncthreads();
  for (int kk = 0; kk < CH; kk += 8) {
    float2 av = make_float2(0.f, 0.f);
    int grow = row0 + sr;
    if (grow < nNodes)
      av = *reinterpret_cast<const float2*>(out + (((long long)grow) << 7) +
                                            kk + skc);
    sA[skc * 68 + sr] = av.x;
    sA[(skc + 1) * 68 + sr] = av.y;
    __syncthreads();
#pragma unroll
    for (int kc = 0; kc < 8; ++kc) {
      int c = kk + kc;
      const float4 w4 = *reinterpret_cast<const float4*>(
          &sWt[(c * CH + (og << 2)) ^ ((c & 31) << 2)]);
      const float4 a0 =
          *reinterpret_cast<const float4*>(&sA[kc * 68 + (rg << 3)]);
      const float4 a1 =
          *reinterpret_cast<const float4*>(&sA[kc * 68 + (rg << 3) + 4]);
      acc[0][0] = fmaf(a0.x, w4.x, acc[0][0]);
      acc[0][1] = fmaf(a0.x, w4.y, acc[0][1]);
      acc[0][2] = fmaf(a0.x, w4.z, acc[0][2]);
      acc[0][3] = fmaf(a0.x, w4.w, acc[0][3]);
      acc[1][0] = fmaf(a0.y, w4.x, acc[1][0]);
      acc[1][1] = fmaf(a0.y, w4.y, acc[1][1]);
      acc[1][2] = fmaf(a0.y, w4.z, acc[1][2]);
      acc[1][3] = fmaf(a0.y, w4.w, acc[1][3]);
      acc[2][0] = fmaf(a0.z, w4.x, acc[2][0]);
      acc[2][1] = fmaf(a0.z, w4.y, acc[2][1]);
      acc[2][2] = fmaf(a0.z, w4.z, acc[2][2]);
      acc[2][3] = fmaf(a0.z, w4.w, acc[2][3]);
      acc[3][0] = fmaf(a0.w, w4.x, acc[3][0]);
      acc[3][1] = fmaf(a0.w, w4.y, acc[3][1]);
      acc[3][2] = fmaf(a0.w, w4.z, acc[3][2]);
      acc[3][3] = fmaf(a0.w, w4.w, acc[3][3]);
      acc[4][0] = fmaf(a1.x, w4.x, acc[4][0]);
      acc[4][1] = fmaf(a1.x, w4.y, acc[4][1]);
      acc[4][2] = fmaf(a1.x, w4.z, acc[4][2]);
      acc[4][3] = fmaf(a1.x, w4.w, acc[4][3]);
      acc[5][0] = fmaf(a1.y, w4.x, acc[5][0]);
      acc[5][1] = fmaf(a1.y, w4.y, acc[5][1]);
      acc[5][2] = fmaf(a1.y, w4.z, acc[5][2]);
      acc[5][3] = fmaf(a1.y, w4.w, acc[5][3]);
      acc[6][0] = fmaf(a1.z, w4.x, acc[6][0]);
      acc[6][1] = fmaf(a1.z, w4.y, acc[6][1]);
      acc[6][2] = fmaf(a1.z, w4.z, acc[6][2]);
      acc[6][3] = fmaf(a1.z, w4.w, acc[6][3]);
      acc[7][0] = fmaf(a1.w, w4.x, acc[7][0]);
      acc[7][1] = fmaf(a1.w, w4.y, acc[7][1]);
      acc[7][2] = fmaf(a1.w, w4.z, acc[7][2]);
      acc[7][3] = fmaf(a1.w, w4.w, acc[7][3]);
    }
    __syncthreads();
  }
  int o0 = og << 2;
  const float4 bv = *reinterpret_cast<const float4*>(&bias[o0]);
#pragma unroll
  for (int i = 0; i < 8; ++i) {
    int r = row0 + (rg << 3) + i;
    if (r < nNodes) {
      float4 res = make_float4(acc[i][0] + bv.x, acc[i][1] + bv.y,
                               acc[i][2] + bv.z, acc[i][3] + bv.w);
      *reinterpret_cast<float4*>(out + (((long long)r) << 7) + o0) = res;
    }
  }
}

extern "C" void kernel_launch(void* const* d_in, const int* in_sizes, int n_in,
                              void* d_out, int out_size, void* d_ws,
                              size_t ws_size, hipStream_t stream) {
  const float* x = (const float*)d_in[0];
  const int* rows = (const int*)d_in[1];
  const int* cols = (const int*)d_in[2];
  const float* vals = (const float*)d_in[3];
  const float* W = (const float*)d_in[4];
  const float* b = (const float*)d_in[5];
  float* out = (float*)d_out;

  int nEdges = in_sizes[1];
  int nNodes = in_sizes[0] / CH;
  int nPrjBlocks = (nNodes + PRJ_ROWS - 1) / PRJ_ROWS;
  int nB = (nNodes + 127) >> 7;

  // ws layout (ints): bptr[nB+1] | cursor[nB] | bcnt[nB] | pad | ecv[2E]
  size_t head = (size_t)(3 * nB + 1);
  size_t ecvOff = (head + 1) & ~(size_t)1;  // 8B align
  size_t needBytes = (ecvOff + 2 * (size_t)nEdges) * 4;

  if (ws_size < needBytes || nB > MAXB || nNodes >= (1 << 25)) {
    hipLaunchKernelGGL(k_init, dim3(2048), dim3(256), 0, stream, (float4*)out,
                       out_size / 4);
    hipLaunchKernelGGL(k_scatter, dim3(4096), dim3(256), 0, stream, x, rows,
                       cols, vals, out, nEdges);
    hipLaunchKernelGGL(k_project, dim3(nPrjBlocks), dim3(256), 0, stream, out,
                       W, b, nNodes);
    return;
  }

  int* wsI = (int*)d_ws;
  int* bptr = wsI;
  int* cursor = bptr + (nB + 1);
  int* bcnt = cursor + nB;
  int2* ecv = (int2*)(wsI + ecvOff);

  int nBinBlocks = (nEdges + BIN_CHUNK - 1) / BIN_CHUNK;

  hipMemsetAsync(bcnt, 0, (size_t)nB * 4, stream);
  hipLaunchKernelGGL(k_histB, dim3(512), dim3(256), 0, stream, rows, bcnt,
                     nEdges, nB);
  hipLaunchKernelGGL(k_scanB, dim3(1), dim3(256), 0, stream, bcnt, bptr,
                     cursor, nB);
  hipLaunchKernelGGL(k_bin, dim3(nBinBlocks), dim3(256), 0, stream, rows, cols,
                     vals, cursor, ecv, nEdges, nB);
  hipLaunchKernelGGL(k_agg, dim3(nB), dim3(AGG_THREADS), 0, stream, x, bptr,
                     ecv, out, nNodes);
  hipLaunchKernelGGL(k_project, dim3(nPrjBlocks), dim3(256), 0, stream, out, W,
                     b, nNodes);
}